// Round 1
// baseline (66.974 us; speedup 1.0000x reference)
//
#include <hip/hip_runtime.h>

// Hadamard transform along channel dim of NCHW fp32 tensor.
// x: [32, 1024, 32, 32], H: Sylvester 1024x1024 (+-1/32) -- H[c,d] = (-1)^popc(c&d)/32.
// out[b,d,s] = sum_c x[b,c,s] * H[c,d]  == normalized FWHT_1024 along c.
// Decompose: H_1024 = H_32 (x) H_32 with c = 32*i + j:
//   pass 1: FWHT_32 over i (fixed j), pass 2: FWHT_32 over j (fixed i), then * 1/32.
//
// Per block: 16 spatial positions x 1024 channels staged in 64 KiB LDS.
// LDS swizzle: channel c=(i<<5)|j stored at slot (i<<5)|(j^i). This makes every
// per-instruction LDS access pattern in both passes exactly 2-way bank aliased
// (free on CDNA4), instead of 4-way for the linear layout.

constexpr int C       = 1024;
constexpr int SPATIAL = 1024;   // 32*32, contiguous innermost
constexpr int S       = 16;     // spatial positions per block (one 64B row per channel)
constexpr int BLOCK   = 512;

__global__ __launch_bounds__(BLOCK) void hadamard_fwht_kernel(
    const float* __restrict__ x, float* __restrict__ out)
{
    __shared__ float lds[C * S];   // 64 KiB

    const int t     = threadIdx.x;
    const int b     = blockIdx.x >> 6;    // 64 chunks of 16 spatial per image
    const int chunk = blockIdx.x & 63;
    const size_t base = ((size_t)b * C) * SPATIAL + (size_t)chunk * S;

    // ---- load: global -> LDS (swizzled). 8 x float4 per thread, 64B segments ----
    #pragma unroll
    for (int k = 0; k < 8; ++k) {
        const int idx4 = t + (k << 9);          // [0, 4096)
        const int c    = idx4 >> 2;             // channel
        const int s4   = idx4 & 3;              // float4 slot within the 16-float row
        const float4 v = *reinterpret_cast<const float4*>(
            x + base + (size_t)c * SPATIAL + (s4 << 2));
        const int i  = c >> 5;
        const int j  = c & 31;
        const int cs = (i << 5) | (j ^ i);      // swizzled channel slot
        *reinterpret_cast<float4*>(&lds[(cs << 4) + (s4 << 2)]) = v;
    }
    __syncthreads();

    float v[32];

    // ---- pass 1: FWHT_32 along i (c = 32*i + j), thread = (j, s) ----
    {
        const int j = t >> 4;
        const int s = t & 15;
        #pragma unroll
        for (int i = 0; i < 32; ++i)
            v[i] = lds[(((i << 5) | (j ^ i)) << 4) + s];

        #pragma unroll
        for (int m = 1; m < 32; m <<= 1)
            #pragma unroll
            for (int g = 0; g < 32; g += (m << 1))
                #pragma unroll
                for (int a = g; a < g + m; ++a) {
                    const float p = v[a], q = v[a + m];
                    v[a]     = p + q;
                    v[a + m] = p - q;
                }

        #pragma unroll
        for (int i = 0; i < 32; ++i)
            lds[(((i << 5) | (j ^ i)) << 4) + s] = v[i];
    }
    __syncthreads();

    // ---- pass 2: FWHT_32 along j, thread = (i, s); scale by 1/32 and store ----
    {
        const int i = t >> 4;
        const int s = t & 15;
        #pragma unroll
        for (int j = 0; j < 32; ++j)
            v[j] = lds[(((i << 5) | (j ^ i)) << 4) + s];

        #pragma unroll
        for (int m = 1; m < 32; m <<= 1)
            #pragma unroll
            for (int g = 0; g < 32; g += (m << 1))
                #pragma unroll
                for (int a = g; a < g + m; ++a) {
                    const float p = v[a], q = v[a + m];
                    v[a]     = p + q;
                    v[a + m] = p - q;
                }

        const float scale = 1.0f / 32.0f;       // 1/sqrt(1024), exact
        float* o = out + base + ((size_t)(i << 5)) * SPATIAL + s;
        #pragma unroll
        for (int j = 0; j < 32; ++j)
            o[(size_t)j * SPATIAL] = v[j] * scale;   // d = (i<<5)|j; 64B segments per i
    }
}

extern "C" void kernel_launch(void* const* d_in, const int* in_sizes, int n_in,
                              void* d_out, int out_size, void* d_ws, size_t ws_size,
                              hipStream_t stream) {
    const float* x = (const float*)d_in[0];
    // d_in[1] (the Hadamard matrix) is not needed: it is the fixed Sylvester
    // construction, which the FWHT computes exactly.
    float* out = (float*)d_out;

    const int blocks = 32 * (SPATIAL / S);   // 32 batches x 64 spatial chunks = 2048
    hadamard_fwht_kernel<<<dim3(blocks), dim3(BLOCK), 0, stream>>>(x, out);
}